// Round 1
// baseline (1072.236 us; speedup 1.0000x reference)
//
#include <hip/hip_runtime.h>
#include <math.h>

#define BB 256
#define TT 512
#define LL 40
#define ED 8
#define NC 22
#define HH 64
#define G3 192   // 3*H

// ws layout:
//   K:  BB floats at byte offset 0
//   X:  BB*TT*32 floats at byte offset 1024   (16 MB)
//       X[b][t][0..7]  = emb-sum, [8..29] = cont, [30] = ccl, [31] = 0

__global__ void kb_kernel(const float* __restrict__ cont, const int* __restrict__ cat,
                          float* __restrict__ K) {
    int b = threadIdx.x;
    if (b >= BB) return;
    float a = cont[(size_t)b * TT * NC + 2]  * 16.936469f + 58.239251f;
    float w = cont[(size_t)b * TT * NC + 21] * 30.519849f + 87.5752f;
    const int* cb = cat + (size_t)b * TT * LL;
    int cnt = 0;
    for (int l = 0; l < LL; ++l) cnt += (cb[l] == 5) ? 1 : 0;
    float g = (float)cnt * 0.15f + 0.85f;
    K[b] = (140.0f - a) * w * g / 72.0f;
}

__global__ void xbuild_kernel(const float* __restrict__ cont, const int* __restrict__ cat,
                              const float* __restrict__ emb, const float* __restrict__ K,
                              float* __restrict__ X) {
    int p = blockIdx.x * 32 + (threadIdx.x >> 3);   // (b,t) pair index
    int e = threadIdx.x & 7;
    int b = p >> 9;                                  // T = 512
    const int* cp = cat + (size_t)p * LL;
    float acc = 0.f;
    #pragma unroll 8
    for (int l = 0; l < LL; ++l) {
        int idx = cp[l];
        acc += emb[idx * ED + e];
    }
    float* xp = X + (size_t)p * 32;
    xp[e] = acc;
    #pragma unroll
    for (int c = e; c < NC; c += 8) xp[8 + c] = cont[(size_t)p * NC + c];
    if (e == 0) {
        float creat = cont[(size_t)p * NC + 11] * 1.418099f + 1.314668f;
        xp[30] = K[b] / creat;
        xp[31] = 0.f;
    }
}

__global__ __launch_bounds__(192) void scan_kernel(
    const float* __restrict__ X,
    const float* __restrict__ lb, const int* __restrict__ mask,
    const float* __restrict__ dvec, const float* __restrict__ td,
    const float* __restrict__ W_ih, const float* __restrict__ W_hh,
    const float* __restrict__ b_ih, const float* __restrict__ b_hh,
    const float* __restrict__ W_out, const float* __restrict__ b_out,
    float* __restrict__ out)
{
    const int b   = blockIdx.x;
    const int tid = threadIdx.x;

    __shared__ __align__(16) float u[96];   // [0..30]=xi(+vfb), [31]=0 pad, [32..95]=h
    __shared__ float g1[G3];                // x-part gates (incl b_ih)
    __shared__ float g2[G3];                // h-part gates (incl b_hh)

    const float* Xb = X + (size_t)b * TT * 32;
    const size_t bT = (size_t)b * TT;

    // Per-lane weight row in registers: w0[0..30]=W_ih row, w0[31]=0 pad, wh[0..63]=W_hh row
    float w0[32];
    #pragma unroll
    for (int k = 0; k < 31; ++k) w0[k] = W_ih[tid * 31 + k];
    w0[31] = 0.f;
    float wh[64];
    #pragma unroll
    for (int k = 0; k < 64; ++k) wh[k] = W_hh[tid * 64 + k];
    const float bi = b_ih[tid];
    const float bh = b_hh[tid];

    float wo0 = 0.f, wo1 = 0.f, wo2 = 0.f, wo3 = 0.f;
    if (tid < HH) {
        wo0 = W_out[0 * HH + tid];
        wo1 = W_out[1 * HH + tid];
        wo2 = W_out[2 * HH + tid];
        wo3 = W_out[3 * HH + tid];
    }
    const float bo0 = b_out[0], bo1 = b_out[1], bo2 = b_out[2], bo3 = b_out[3];

    float hreg = 0.f;           // lane j<64 owns h_j
    float Cc = 0.f, Dc = 0.f;   // lane 0 PK state

    // init u for t=0: xi(t=0), vfb(0)=0, h(-1)=0
    if (tid < 30) u[tid] = Xb[tid];
    if (tid == 30) u[30] = 0.f;
    if (tid == 31) u[31] = 0.f;
    if (tid < HH) u[32 + tid] = 0.f;

    for (int t = 0; t < TT; ++t) {
        __syncthreads();   // u complete: xi(t), vfb(t), h(t-1)

        // early-issue next-step feature loads + this-step scalars
        float xnext = 0.f;
        if (tid < 30) {
            int tn = (t + 1 < TT) ? (t + 1) : t;
            xnext = Xb[tn * 32 + tid];
        }
        float cc = 0.f, dd = 0.f, tt = 0.f, mpn = 0.f, lpn = 0.f;
        if (tid == 0) {
            cc  = Xb[t * 32 + 30];
            dd  = dvec[bT + t];
            tt  = td[bT + t] * 24.0f;
            mpn = (float)mask[bT + t];
            lpn = lb[bT + t];
        }

        // gate dots: acc1 = xi . w0 + bi ; acc2 = h . wh + bh  (u broadcast from LDS)
        const float4* u4 = (const float4*)u;
        float a1a = 0.f, a1b = 0.f;
        #pragma unroll
        for (int k = 0; k < 8; k += 2) {
            float4 ua = u4[k];
            a1a = fmaf(ua.x, w0[4 * k + 0], a1a);
            a1a = fmaf(ua.y, w0[4 * k + 1], a1a);
            a1a = fmaf(ua.z, w0[4 * k + 2], a1a);
            a1a = fmaf(ua.w, w0[4 * k + 3], a1a);
            float4 ub = u4[k + 1];
            a1b = fmaf(ub.x, w0[4 * k + 4], a1b);
            a1b = fmaf(ub.y, w0[4 * k + 5], a1b);
            a1b = fmaf(ub.z, w0[4 * k + 6], a1b);
            a1b = fmaf(ub.w, w0[4 * k + 7], a1b);
        }
        const float acc1 = bi + a1a + a1b;

        float a2a = 0.f, a2b = 0.f, a2c = 0.f, a2d = 0.f;
        #pragma unroll
        for (int k = 0; k < 16; k += 4) {
            float4 v0 = u4[8 + k], v1 = u4[9 + k], v2 = u4[10 + k], v3 = u4[11 + k];
            a2a = fmaf(v0.x, wh[4 * k + 0],  a2a);
            a2a = fmaf(v0.y, wh[4 * k + 1],  a2a);
            a2a = fmaf(v0.z, wh[4 * k + 2],  a2a);
            a2a = fmaf(v0.w, wh[4 * k + 3],  a2a);
            a2b = fmaf(v1.x, wh[4 * k + 4],  a2b);
            a2b = fmaf(v1.y, wh[4 * k + 5],  a2b);
            a2b = fmaf(v1.z, wh[4 * k + 6],  a2b);
            a2b = fmaf(v1.w, wh[4 * k + 7],  a2b);
            a2c = fmaf(v2.x, wh[4 * k + 8],  a2c);
            a2c = fmaf(v2.y, wh[4 * k + 9],  a2c);
            a2c = fmaf(v2.z, wh[4 * k + 10], a2c);
            a2c = fmaf(v2.w, wh[4 * k + 11], a2c);
            a2d = fmaf(v3.x, wh[4 * k + 12], a2d);
            a2d = fmaf(v3.y, wh[4 * k + 13], a2d);
            a2d = fmaf(v3.z, wh[4 * k + 14], a2d);
            a2d = fmaf(v3.w, wh[4 * k + 15], a2d);
        }
        const float acc2 = bh + ((a2a + a2b) + (a2c + a2d));

        g1[tid] = acc1;
        g2[tid] = acc2;
        __syncthreads();   // gates ready; all reads of u done

        if (tid < HH) {
            // GRU update for hidden unit tid
            float pre_r = g1[tid] + g2[tid];
            float pre_z = g1[tid + HH] + g2[tid + HH];
            float r = 1.0f / (1.0f + expf(-pre_r));
            float z = 1.0f / (1.0f + expf(-pre_z));
            float n = tanhf(g1[tid + 2 * HH] + r * g2[tid + 2 * HH]);
            hreg = (1.0f - z) * n + z * hreg;
            u[32 + tid] = hreg;

            // eta = h . W_out^T  (4 butterfly reductions over wave 0)
            float p0 = hreg * wo0, p1 = hreg * wo1, p2 = hreg * wo2, p3 = hreg * wo3;
            #pragma unroll
            for (int off = 32; off > 0; off >>= 1) {
                p0 += __shfl_xor(p0, off);
                p1 += __shfl_xor(p1, off);
                p2 += __shfl_xor(p2, off);
                p3 += __shfl_xor(p3, off);
            }
            if (tid == 0) {
                float e1 = p0 + bo0, e2 = p1 + bo1, e3 = p2 + bo2, e4 = p3 + bo3;
                float v1  = 33.1f * expf(e1);
                float k1  = 3.96f * cc / 100.0f * expf(e2);
                float rrr = 1000.0f / v1;
                float v2  = 48.3f * expf(e4);
                float R   = (-6.99f / 48.3f) * expf(e3);
                float k2  = R * v2;
                float q   = k1 - k2 - R * v1;
                float delta = sqrtf(q * q + 4.0f * k1 * R * v1) / v1;
                float s1  = (-k1 + k2 + R * v1) / v1;
                float lam1 = (s1 - delta) * 0.5f;
                float lam2 = (s1 + delta) * 0.5f;
                float kv  = k2 / v1;
                float C1  = rrr * kv / lam1 / delta;
                float C2  = -rrr * kv / lam2 / delta;
                float C3  = -(lam1 - R) / kv;
                float C4  = -(lam2 - R) / kv;
                float Cn  = ((Cc + C1) * expf(lam1 * dd) - C1) * expf(lam1 * (tt - dd));
                float Dn  = ((Dc + C2) * expf(lam2 * dd) - C2) * expf(lam2 * (tt - dd));
                float An  = Cn * C3 + Dn * C4;
                out[bT + t] = An;
                Cc = Cn;
                Dc = Dn;
                // vfb for step t+1 uses mask[t], lb[t]
                u[30] = An * (1.0f - mpn) + lpn * mpn;
            }
        }
        if (tid < 30) u[tid] = xnext;   // xi for t+1
    }
}

extern "C" void kernel_launch(void* const* d_in, const int* in_sizes, int n_in,
                              void* d_out, int out_size, void* d_ws, size_t ws_size,
                              hipStream_t stream) {
    const float* cont  = (const float*)d_in[0];
    const int*   cat   = (const int*)  d_in[1];
    const float* lb    = (const float*)d_in[2];
    const int*   mask  = (const int*)  d_in[3];
    const float* dvec  = (const float*)d_in[4];
    const float* td    = (const float*)d_in[5];
    const float* emb   = (const float*)d_in[6];
    const float* W_ih  = (const float*)d_in[7];
    const float* W_hh  = (const float*)d_in[8];
    const float* b_ih  = (const float*)d_in[9];
    const float* b_hh  = (const float*)d_in[10];
    const float* W_out = (const float*)d_in[11];
    const float* b_out = (const float*)d_in[12];
    float* out = (float*)d_out;

    float* K = (float*)d_ws;
    float* X = (float*)((char*)d_ws + 1024);

    hipLaunchKernelGGL(kb_kernel, dim3(1), dim3(256), 0, stream, cont, cat, K);
    hipLaunchKernelGGL(xbuild_kernel, dim3((BB * TT) / 32), dim3(256), 0, stream,
                       cont, cat, emb, K, X);
    hipLaunchKernelGGL(scan_kernel, dim3(BB), dim3(192), 0, stream,
                       X, lb, mask, dvec, td, W_ih, W_hh, b_ih, b_hh, W_out, b_out, out);
}

// Round 2
// 711.982 us; speedup vs baseline: 1.5060x; 1.5060x over previous
//
#include <hip/hip_runtime.h>
#include <math.h>

#define BB 256
#define TT 512
#define LL 40
#define ED 8
#define NC 22
#define HH 64
#define G3 192   // 3*H

// ws layout:
//   K:  BB floats at byte offset 0
//   X:  BB*TT*32 floats at byte offset 1024   (16 MB)
//       X[b][t][0..7]  = emb-sum, [8..29] = cont, [30] = ccl, [31] = 0

__global__ void kb_kernel(const float* __restrict__ cont, const int* __restrict__ cat,
                          float* __restrict__ K) {
    int b = threadIdx.x;
    if (b >= BB) return;
    float a = cont[(size_t)b * TT * NC + 2]  * 16.936469f + 58.239251f;
    float w = cont[(size_t)b * TT * NC + 21] * 30.519849f + 87.5752f;
    const int* cb = cat + (size_t)b * TT * LL;
    int cnt = 0;
    for (int l = 0; l < LL; ++l) cnt += (cb[l] == 5) ? 1 : 0;
    float g = (float)cnt * 0.15f + 0.85f;
    K[b] = (140.0f - a) * w * g / 72.0f;
}

__global__ void xbuild_kernel(const float* __restrict__ cont, const int* __restrict__ cat,
                              const float* __restrict__ emb, const float* __restrict__ K,
                              float* __restrict__ X) {
    int p = blockIdx.x * 32 + (threadIdx.x >> 3);   // (b,t) pair index
    int e = threadIdx.x & 7;
    int b = p >> 9;                                  // T = 512
    const int* cp = cat + (size_t)p * LL;
    float acc = 0.f;
    #pragma unroll 8
    for (int l = 0; l < LL; ++l) {
        int idx = cp[l];
        acc += emb[idx * ED + e];
    }
    float* xp = X + (size_t)p * 32;
    xp[e] = acc;
    #pragma unroll
    for (int c = e; c < NC; c += 8) xp[8 + c] = cont[(size_t)p * NC + c];
    if (e == 0) {
        float creat = cont[(size_t)p * NC + 11] * 1.418099f + 1.314668f;
        xp[30] = K[b] / creat;
        xp[31] = 0.f;
    }
}

__device__ __forceinline__ float fast_rcp(float x) { return __builtin_amdgcn_rcpf(x); }

__device__ __forceinline__ float fast_sig(float x) {
    return fast_rcp(1.0f + __expf(-x));
}

__device__ __forceinline__ float fast_tanh(float x) {
    float E = __expf(2.0f * x);
    return 1.0f - 2.0f * fast_rcp(E + 1.0f);
}

// wave64 all-lanes sum: 4 DPP xor-steps (1,2,4,8) + shfl_xor(16,32)
__device__ __forceinline__ float wave_reduce_add(float x) {
    int v;
    v = __builtin_amdgcn_update_dpp(0, __float_as_int(x), 0xB1, 0xF, 0xF, true);  // quad_perm [1,0,3,2]
    x += __int_as_float(v);
    v = __builtin_amdgcn_update_dpp(0, __float_as_int(x), 0x4E, 0xF, 0xF, true);  // quad_perm [2,3,0,1]
    x += __int_as_float(v);
    v = __builtin_amdgcn_update_dpp(0, __float_as_int(x), 0x141, 0xF, 0xF, true); // row_half_mirror (xor4)
    x += __int_as_float(v);
    v = __builtin_amdgcn_update_dpp(0, __float_as_int(x), 0x140, 0xF, 0xF, true); // row_mirror (xor8)
    x += __int_as_float(v);
    x += __shfl_xor(x, 16);
    x += __shfl_xor(x, 32);
    return x;
}

__global__ __launch_bounds__(192, 1) void scan_kernel(
    const float* __restrict__ X,
    const float* __restrict__ lb, const int* __restrict__ mask,
    const float* __restrict__ dvec, const float* __restrict__ td,
    const float* __restrict__ W_ih, const float* __restrict__ W_hh,
    const float* __restrict__ b_ih, const float* __restrict__ b_hh,
    const float* __restrict__ W_out, const float* __restrict__ b_out,
    float* __restrict__ out)
{
    const int b   = blockIdx.x;
    const int tid = threadIdx.x;

    __shared__ __align__(16) float u[96];   // [0..30]=xi(+vfb), [31]=0 pad, [32..95]=h
    __shared__ float g1[G3];                // x-part gates (incl b_ih)
    __shared__ float g2[G3];                // h-part gates (incl b_hh)

    const float* Xb = X + (size_t)b * TT * 32;
    const size_t bT = (size_t)b * TT;

    // Per-lane weight row in registers (launch_bounds(192,1) -> VGPR budget up to 512,
    // so w0[32]+wh[64] stay register-resident instead of re-loading from L2 each step)
    float w0[32];
    #pragma unroll
    for (int k = 0; k < 31; ++k) w0[k] = W_ih[tid * 31 + k];
    w0[31] = 0.f;
    float wh[64];
    #pragma unroll
    for (int k = 0; k < 64; ++k) wh[k] = W_hh[tid * 64 + k];
    const float bi = b_ih[tid];
    const float bh = b_hh[tid];

    float wo0 = 0.f, wo1 = 0.f, wo2 = 0.f, wo3 = 0.f;
    if (tid < HH) {
        wo0 = W_out[0 * HH + tid];
        wo1 = W_out[1 * HH + tid];
        wo2 = W_out[2 * HH + tid];
        wo3 = W_out[3 * HH + tid];
    }
    const float bo0 = b_out[0], bo1 = b_out[1], bo2 = b_out[2], bo3 = b_out[3];

    float hreg = 0.f;           // lane j<64 owns h_j
    float Cc = 0.f, Dc = 0.f;   // PK state (uniform across wave 0)

    // current-step scalars (uniform across wave 0), preloaded for t=0
    float cc = 0.f, dd = 0.f, tt = 0.f, mpn = 0.f, lpn = 0.f;
    if (tid < HH) {
        cc  = Xb[30];
        dd  = dvec[bT];
        tt  = td[bT] * 24.0f;
        mpn = (float)mask[bT];
        lpn = lb[bT];
    }

    // init u for t=0: xi(t=0), vfb(0)=0, h(-1)=0
    if (tid < 30) u[tid] = Xb[tid];
    if (tid == 30) u[30] = 0.f;
    if (tid == 31) u[31] = 0.f;
    if (tid < HH) u[32 + tid] = 0.f;

    for (int t = 0; t < TT; ++t) {
        __syncthreads();   // u complete: xi(t), vfb(t), h(t-1)

        // early-issue next-step feature + scalar loads (hidden under the dot phase)
        const int tn = (t + 1 < TT) ? (t + 1) : t;
        float xnext = 0.f;
        if (tid < 30) xnext = Xb[tn * 32 + tid];
        float cc_n = 0.f, dd_n = 0.f, tt_n = 0.f, mp_n = 0.f, lp_n = 0.f;
        if (tid < HH) {
            cc_n = Xb[tn * 32 + 30];
            dd_n = dvec[bT + tn];
            tt_n = td[bT + tn] * 24.0f;
            mp_n = (float)mask[bT + tn];
            lp_n = lb[bT + tn];
        }

        // gate dots: acc1 = xi . w0 + bi ; acc2 = h . wh + bh  (u broadcast from LDS)
        const float4* u4 = (const float4*)u;
        float a1a = 0.f, a1b = 0.f;
        #pragma unroll
        for (int k = 0; k < 8; k += 2) {
            float4 ua = u4[k];
            a1a = fmaf(ua.x, w0[4 * k + 0], a1a);
            a1a = fmaf(ua.y, w0[4 * k + 1], a1a);
            a1a = fmaf(ua.z, w0[4 * k + 2], a1a);
            a1a = fmaf(ua.w, w0[4 * k + 3], a1a);
            float4 ub = u4[k + 1];
            a1b = fmaf(ub.x, w0[4 * k + 4], a1b);
            a1b = fmaf(ub.y, w0[4 * k + 5], a1b);
            a1b = fmaf(ub.z, w0[4 * k + 6], a1b);
            a1b = fmaf(ub.w, w0[4 * k + 7], a1b);
        }
        const float acc1 = bi + a1a + a1b;

        float a2a = 0.f, a2b = 0.f, a2c = 0.f, a2d = 0.f;
        #pragma unroll
        for (int k = 0; k < 16; k += 4) {
            float4 v0 = u4[8 + k], v1 = u4[9 + k], v2 = u4[10 + k], v3 = u4[11 + k];
            a2a = fmaf(v0.x, wh[4 * k + 0],  a2a);
            a2a = fmaf(v0.y, wh[4 * k + 1],  a2a);
            a2a = fmaf(v0.z, wh[4 * k + 2],  a2a);
            a2a = fmaf(v0.w, wh[4 * k + 3],  a2a);
            a2b = fmaf(v1.x, wh[4 * k + 4],  a2b);
            a2b = fmaf(v1.y, wh[4 * k + 5],  a2b);
            a2b = fmaf(v1.z, wh[4 * k + 6],  a2b);
            a2b = fmaf(v1.w, wh[4 * k + 7],  a2b);
            a2c = fmaf(v2.x, wh[4 * k + 8],  a2c);
            a2c = fmaf(v2.y, wh[4 * k + 9],  a2c);
            a2c = fmaf(v2.z, wh[4 * k + 10], a2c);
            a2c = fmaf(v2.w, wh[4 * k + 11], a2c);
            a2d = fmaf(v3.x, wh[4 * k + 12], a2d);
            a2d = fmaf(v3.y, wh[4 * k + 13], a2d);
            a2d = fmaf(v3.z, wh[4 * k + 14], a2d);
            a2d = fmaf(v3.w, wh[4 * k + 15], a2d);
        }
        const float acc2 = bh + ((a2a + a2b) + (a2c + a2d));

        g1[tid] = acc1;
        g2[tid] = acc2;
        __syncthreads();   // gates ready; all reads of u done

        if (tid < HH) {
            // GRU update for hidden unit tid (row tid is the r-row: acc1/acc2 local)
            float pre_r = acc1 + acc2;
            float pre_z = g1[tid + HH] + g2[tid + HH];
            float r = fast_sig(pre_r);
            float z = fast_sig(pre_z);
            float n = fast_tanh(fmaf(r, g2[tid + 2 * HH], g1[tid + 2 * HH]));
            hreg = fmaf(z, hreg - n, n);          // (1-z)*n + z*h
            u[32 + tid] = hreg;

            // eta = h . W_out^T : 4 all-lane butterfly sums (DPP + 2 shuffles)
            float p0 = wave_reduce_add(hreg * wo0);
            float p1 = wave_reduce_add(hreg * wo1);
            float p2 = wave_reduce_add(hreg * wo2);
            float p3 = wave_reduce_add(hreg * wo3);

            // PK chain — uniform across all 64 lanes of wave 0 (no divergence),
            // native exp/rcp/sqrt (threshold has ~8x headroom over current absmax)
            float E1 = __expf(p0 + bo0);
            float E2 = __expf(p1 + bo1);
            float E3 = __expf(p2 + bo2);
            float E4 = __expf(p3 + bo3);
            float v1  = 33.1f * E1;
            float rv1 = fast_rcp(v1);
            float k1  = 3.96f * cc * 0.01f * E2;
            float rrr = 1000.0f * rv1;
            float v2  = 48.3f * E4;
            float R   = (-6.99f / 48.3f) * E3;
            float k2  = R * v2;
            float q   = k1 - k2 - R * v1;
            float disc = fmaf(q, q, 4.0f * k1 * R * v1);
            float delta = __builtin_amdgcn_sqrtf(disc) * rv1;
            float s1  = (k2 - k1 + R * v1) * rv1;
            float lam1 = (s1 - delta) * 0.5f;
            float lam2 = (s1 + delta) * 0.5f;
            float kv  = k2 * rv1;
            float rkv = fast_rcp(kv);
            float C1  = rrr * kv * fast_rcp(lam1 * delta);
            float C2  = -rrr * kv * fast_rcp(lam2 * delta);
            float C3  = -(lam1 - R) * rkv;
            float C4  = -(lam2 - R) * rkv;
            float Cn  = fmaf(Cc + C1, __expf(lam1 * dd), -C1) * __expf(lam1 * (tt - dd));
            float Dn  = fmaf(Dc + C2, __expf(lam2 * dd), -C2) * __expf(lam2 * (tt - dd));
            float An  = fmaf(Cn, C3, Dn * C4);
            Cc = Cn;
            Dc = Dn;
            if (tid == 0) {
                out[bT + t] = An;
                // vfb for step t+1 uses mask[t], lb[t]
                u[30] = An * (1.0f - mpn) + lpn * mpn;
            }
            // rotate prefetched scalars
            cc = cc_n; dd = dd_n; tt = tt_n; mpn = mp_n; lpn = lp_n;
        }
        if (tid < 30) u[tid] = xnext;   // xi for t+1
    }
}

extern "C" void kernel_launch(void* const* d_in, const int* in_sizes, int n_in,
                              void* d_out, int out_size, void* d_ws, size_t ws_size,
                              hipStream_t stream) {
    const float* cont  = (const float*)d_in[0];
    const int*   cat   = (const int*)  d_in[1];
    const float* lb    = (const float*)d_in[2];
    const int*   mask  = (const int*)  d_in[3];
    const float* dvec  = (const float*)d_in[4];
    const float* td    = (const float*)d_in[5];
    const float* emb   = (const float*)d_in[6];
    const float* W_ih  = (const float*)d_in[7];
    const float* W_hh  = (const float*)d_in[8];
    const float* b_ih  = (const float*)d_in[9];
    const float* b_hh  = (const float*)d_in[10];
    const float* W_out = (const float*)d_in[11];
    const float* b_out = (const float*)d_in[12];
    float* out = (float*)d_out;

    float* K = (float*)d_ws;
    float* X = (float*)((char*)d_ws + 1024);

    hipLaunchKernelGGL(kb_kernel, dim3(1), dim3(256), 0, stream, cont, cat, K);
    hipLaunchKernelGGL(xbuild_kernel, dim3((BB * TT) / 32), dim3(256), 0, stream,
                       cont, cat, emb, K, X);
    hipLaunchKernelGGL(scan_kernel, dim3(BB), dim3(192), 0, stream,
                       X, lb, mask, dvec, td, W_ih, W_hh, b_ih, b_hh, W_out, b_out, out);
}

// Round 3
// 654.820 us; speedup vs baseline: 1.6375x; 1.0873x over previous
//
#include <hip/hip_runtime.h>
#include <math.h>

#define BB 256
#define TT 512
#define LL 40
#define ED 8
#define NC 22
#define HH 64
#define G3 192   // 3*H

// ws layout:
//   Xs: BB*TT*8 floats at byte offset 0 (4 MB) — per-(b,t) embedding sums

__global__ void xbuild_kernel(const int* __restrict__ cat, const float* __restrict__ emb,
                              float* __restrict__ Xs) {
    int gid = blockIdx.x * 256 + threadIdx.x;
    int p = gid >> 3;          // (b,t) pair
    int e = gid & 7;           // emb column
    const int* cp = cat + (size_t)p * LL;
    float acc = 0.f;
    #pragma unroll 8
    for (int l = 0; l < LL; ++l) {
        int idx = cp[l];
        acc += emb[idx * ED + e];
    }
    Xs[gid] = acc;
}

__device__ __forceinline__ float fast_rcp(float x) { return __builtin_amdgcn_rcpf(x); }

__device__ __forceinline__ float fast_sig(float x) {
    return fast_rcp(1.0f + __expf(-x));
}

__device__ __forceinline__ float fast_tanh(float x) {
    float E = __expf(2.0f * x);
    return 1.0f - 2.0f * fast_rcp(E + 1.0f);
}

// wave64 all-lanes sum: 4 DPP xor-steps (1,2,4,8) + shfl_xor(16,32)
__device__ __forceinline__ float wave_reduce_add(float x) {
    int v;
    v = __builtin_amdgcn_update_dpp(0, __float_as_int(x), 0xB1, 0xF, 0xF, true);  // quad_perm [1,0,3,2]
    x += __int_as_float(v);
    v = __builtin_amdgcn_update_dpp(0, __float_as_int(x), 0x4E, 0xF, 0xF, true);  // quad_perm [2,3,0,1]
    x += __int_as_float(v);
    v = __builtin_amdgcn_update_dpp(0, __float_as_int(x), 0x141, 0xF, 0xF, true); // row_half_mirror (xor4)
    x += __int_as_float(v);
    v = __builtin_amdgcn_update_dpp(0, __float_as_int(x), 0x140, 0xF, 0xF, true); // row_mirror (xor8)
    x += __int_as_float(v);
    x += __shfl_xor(x, 16);
    x += __shfl_xor(x, 32);
    return x;
}

__global__ __launch_bounds__(192, 1) void scan_kernel(
    const float* __restrict__ Xs, const float* __restrict__ cont,
    const float* __restrict__ cat_unused,
    const int* __restrict__ cat,
    const float* __restrict__ lb, const int* __restrict__ mask,
    const float* __restrict__ dvec, const float* __restrict__ td,
    const float* __restrict__ W_ih, const float* __restrict__ W_hh,
    const float* __restrict__ b_ih, const float* __restrict__ b_hh,
    const float* __restrict__ W_out, const float* __restrict__ b_out,
    float* __restrict__ out)
{
    const int b   = blockIdx.x;
    const int tid = threadIdx.x;

    __shared__ __align__(16) float u[96];   // [0..7]=emb, [8..29]=cont, [30]=vfb, [31]=0, [32..95]=h
    __shared__ float g1[G3];                // x-part gates (incl b_ih)
    __shared__ float g2[G3];                // h-part gates (incl b_hh)

    const float* Xb   = Xs  + (size_t)b * TT * 8;
    const float* contb = cont + (size_t)b * TT * NC;
    const size_t bT = (size_t)b * TT;

    // ---- weight rows in registers, PINNED so the compiler cannot sink the
    // loads back into the loop (R2 post-mortem: VGPR_Count=72 proved it did) ----
    float w0[32];
    #pragma unroll
    for (int k = 0; k < 31; ++k) w0[k] = W_ih[tid * 31 + k];
    w0[31] = 0.f;
    float wh[64];
    #pragma unroll
    for (int k = 0; k < 64; ++k) wh[k] = W_hh[tid * 64 + k];
    #pragma unroll
    for (int k = 0; k < 32; ++k) asm volatile("" : "+v"(w0[k]));
    #pragma unroll
    for (int k = 0; k < 64; ++k) asm volatile("" : "+v"(wh[k]));
    const float bi = b_ih[tid];
    const float bh = b_hh[tid];

    float wo0 = 0.f, wo1 = 0.f, wo2 = 0.f, wo3 = 0.f;
    if (tid < HH) {
        wo0 = W_out[0 * HH + tid];
        wo1 = W_out[1 * HH + tid];
        wo2 = W_out[2 * HH + tid];
        wo3 = W_out[3 * HH + tid];
    }
    const float bo0 = b_out[0], bo1 = b_out[1], bo2 = b_out[2], bo3 = b_out[3];

    float hreg = 0.f;           // wave0 lane j owns h_j
    float Cc = 0.f, Dc = 0.f;   // PK state (uniform across wave 0)

    // ---- prologue: K[b] computed in-wave (replaces kb_kernel) ----
    float Kb = 0.f;
    float cc = 0.f, dd = 0.f, tt = 0.f, mpn = 0.f, lpn = 0.f;
    if (tid < HH) {
        int cv = (tid < LL) ? cat[(size_t)b * TT * LL + tid] : 0;
        unsigned long long bal = __ballot(tid < LL && cv == 5);
        float g   = (float)__popcll(bal) * 0.15f + 0.85f;
        float age = contb[2]  * 16.936469f + 58.239251f;
        float wgt = contb[21] * 30.519849f + 87.5752f;
        Kb = (140.0f - age) * wgt * g / 72.0f;
        // scalars for t=0
        cc  = Kb * fast_rcp(fmaf(contb[11], 1.418099f, 1.314668f));
        dd  = dvec[bT];
        tt  = td[bT] * 24.0f;
        mpn = (float)mask[bT];
        lpn = lb[bT];
        u[32 + tid] = 0.f;                 // h(-1) = 0
        if (tid == 0) { u[30] = 0.f; u[31] = 0.f; }
    }
    // u[0..29] for t=0 filled by wave 1
    if (tid >= 64 && tid < 94) {
        int i = tid - 64;
        u[i] = (i < 8) ? Xb[i] : contb[i - 8];
    }

    for (int t = 0; t < TT; ++t) {
        __syncthreads();   // u complete: xi(t), vfb(t), h(t-1)

        const int tn = (t + 1 < TT) ? (t + 1) : t;

        // wave1 prefetches next-step features (written to u after barrier 2)
        float xnext = 0.f;
        if (tid >= 64 && tid < 94) {
            int i = tid - 64;
            xnext = (i < 8) ? Xb[tn * 8 + i] : contb[tn * NC + (i - 8)];
        }
        // wave0 prefetches next-step scalars
        float cc_n = 0.f, dd_n = 0.f, tt_n = 0.f, mp_n = 0.f, lp_n = 0.f;
        if (tid < HH) {
            cc_n = Kb * fast_rcp(fmaf(contb[tn * NC + 11], 1.418099f, 1.314668f));
            dd_n = dvec[bT + tn];
            tt_n = td[bT + tn] * 24.0f;
            mp_n = (float)mask[bT + tn];
            lp_n = lb[bT + tn];
        }

        // gate dots: acc1 = xi . w0 + bi ; acc2 = h . wh + bh  (u broadcast from LDS)
        const float4* u4 = (const float4*)u;
        float a1a = 0.f, a1b = 0.f;
        #pragma unroll
        for (int k = 0; k < 8; k += 2) {
            float4 ua = u4[k];
            a1a = fmaf(ua.x, w0[4 * k + 0], a1a);
            a1a = fmaf(ua.y, w0[4 * k + 1], a1a);
            a1a = fmaf(ua.z, w0[4 * k + 2], a1a);
            a1a = fmaf(ua.w, w0[4 * k + 3], a1a);
            float4 ub = u4[k + 1];
            a1b = fmaf(ub.x, w0[4 * k + 4], a1b);
            a1b = fmaf(ub.y, w0[4 * k + 5], a1b);
            a1b = fmaf(ub.z, w0[4 * k + 6], a1b);
            a1b = fmaf(ub.w, w0[4 * k + 7], a1b);
        }
        const float acc1 = bi + a1a + a1b;

        float a2a = 0.f, a2b = 0.f, a2c = 0.f, a2d = 0.f;
        #pragma unroll
        for (int k = 0; k < 16; k += 4) {
            float4 v0 = u4[8 + k], v1 = u4[9 + k], v2 = u4[10 + k], v3 = u4[11 + k];
            a2a = fmaf(v0.x, wh[4 * k + 0],  a2a);
            a2a = fmaf(v0.y, wh[4 * k + 1],  a2a);
            a2a = fmaf(v0.z, wh[4 * k + 2],  a2a);
            a2a = fmaf(v0.w, wh[4 * k + 3],  a2a);
            a2b = fmaf(v1.x, wh[4 * k + 4],  a2b);
            a2b = fmaf(v1.y, wh[4 * k + 5],  a2b);
            a2b = fmaf(v1.z, wh[4 * k + 6],  a2b);
            a2b = fmaf(v1.w, wh[4 * k + 7],  a2b);
            a2c = fmaf(v2.x, wh[4 * k + 8],  a2c);
            a2c = fmaf(v2.y, wh[4 * k + 9],  a2c);
            a2c = fmaf(v2.z, wh[4 * k + 10], a2c);
            a2c = fmaf(v2.w, wh[4 * k + 11], a2c);
            a2d = fmaf(v3.x, wh[4 * k + 12], a2d);
            a2d = fmaf(v3.y, wh[4 * k + 13], a2d);
            a2d = fmaf(v3.z, wh[4 * k + 14], a2d);
            a2d = fmaf(v3.w, wh[4 * k + 15], a2d);
        }
        const float acc2 = bh + ((a2a + a2b) + (a2c + a2d));

        g1[tid] = acc1;
        g2[tid] = acc2;
        __syncthreads();   // gates ready; all reads of u done

        // wave1: publish next-step features (off wave0's critical path)
        if (tid >= 64 && tid < 94) u[tid - 64] = xnext;

        if (tid < HH) {
            // GRU update for hidden unit tid (row tid is the r-row: acc1/acc2 local)
            float pre_r = acc1 + acc2;
            float pre_z = g1[tid + HH] + g2[tid + HH];
            float r = fast_sig(pre_r);
            float z = fast_sig(pre_z);
            float n = fast_tanh(fmaf(r, g2[tid + 2 * HH], g1[tid + 2 * HH]));
            hreg = fmaf(z, hreg - n, n);          // (1-z)*n + z*h
            u[32 + tid] = hreg;

            // eta = h . W_out^T : 4 all-lane butterfly sums
            float p0 = wave_reduce_add(hreg * wo0);
            float p1 = wave_reduce_add(hreg * wo1);
            float p2 = wave_reduce_add(hreg * wo2);
            float p3 = wave_reduce_add(hreg * wo3);

            // PK chain — uniform across wave 0 (no divergence), native exp/rcp/sqrt
            float E1 = __expf(p0 + bo0);
            float E2 = __expf(p1 + bo1);
            float E3 = __expf(p2 + bo2);
            float E4 = __expf(p3 + bo3);
            float v1  = 33.1f * E1;
            float rv1 = fast_rcp(v1);
            float k1  = 3.96f * cc * 0.01f * E2;
            float rrr = 1000.0f * rv1;
            float v2  = 48.3f * E4;
            float R   = (-6.99f / 48.3f) * E3;
            float k2  = R * v2;
            float q   = k1 - k2 - R * v1;
            float disc = fmaf(q, q, 4.0f * k1 * R * v1);
            float delta = __builtin_amdgcn_sqrtf(disc) * rv1;
            float s1  = (k2 - k1 + R * v1) * rv1;
            float lam1 = (s1 - delta) * 0.5f;
            float lam2 = (s1 + delta) * 0.5f;
            float kv  = k2 * rv1;
            float rkv = fast_rcp(kv);
            float C1  = rrr * kv * fast_rcp(lam1 * delta);
            float C2  = -rrr * kv * fast_rcp(lam2 * delta);
            float C3  = -(lam1 - R) * rkv;
            float C4  = -(lam2 - R) * rkv;
            float Cn  = fmaf(Cc + C1, __expf(lam1 * dd), -C1) * __expf(lam1 * (tt - dd));
            float Dn  = fmaf(Dc + C2, __expf(lam2 * dd), -C2) * __expf(lam2 * (tt - dd));
            float An  = fmaf(Cn, C3, Dn * C4);
            Cc = Cn;
            Dc = Dn;
            if (tid == 0) {
                out[bT + t] = An;
                u[30] = An * (1.0f - mpn) + lpn * mpn;   // vfb for t+1
            }
            // rotate prefetched scalars
            cc = cc_n; dd = dd_n; tt = tt_n; mpn = mp_n; lpn = lp_n;
        }
    }
}

extern "C" void kernel_launch(void* const* d_in, const int* in_sizes, int n_in,
                              void* d_out, int out_size, void* d_ws, size_t ws_size,
                              hipStream_t stream) {
    const float* cont  = (const float*)d_in[0];
    const int*   cat   = (const int*)  d_in[1];
    const float* lb    = (const float*)d_in[2];
    const int*   mask  = (const int*)  d_in[3];
    const float* dvec  = (const float*)d_in[4];
    const float* td    = (const float*)d_in[5];
    const float* emb   = (const float*)d_in[6];
    const float* W_ih  = (const float*)d_in[7];
    const float* W_hh  = (const float*)d_in[8];
    const float* b_ih  = (const float*)d_in[9];
    const float* b_hh  = (const float*)d_in[10];
    const float* W_out = (const float*)d_in[11];
    const float* b_out = (const float*)d_in[12];
    float* out = (float*)d_out;

    float* Xs = (float*)d_ws;

    hipLaunchKernelGGL(xbuild_kernel, dim3((BB * TT * 8) / 256), dim3(256), 0, stream,
                       cat, emb, Xs);
    hipLaunchKernelGGL(scan_kernel, dim3(BB), dim3(192), 0, stream,
                       Xs, cont, (const float*)nullptr, cat,
                       lb, mask, dvec, td, W_ih, W_hh, b_ih, b_hh, W_out, b_out, out);
}

// Round 4
// 589.758 us; speedup vs baseline: 1.8181x; 1.1103x over previous
//
#include <hip/hip_runtime.h>
#include <math.h>

#define BB 256
#define TT 512
#define LL 40
#define ED 8
#define NC 22
#define HH 64
#define G3 192   // 3*H

// ws layout:
//   X: BB*TT*32 floats (16 MB) — feat rows: [0..7]=emb-sum, [8..29]=cont, [30]=0(vfb slot), [31]=0

__global__ void xbuild_kernel(const float* __restrict__ cont, const int* __restrict__ cat,
                              const float* __restrict__ emb, float* __restrict__ X) {
    int p = blockIdx.x * 32 + (threadIdx.x >> 3);   // (b,t) pair index
    int e = threadIdx.x & 7;
    const int* cp = cat + (size_t)p * LL;
    float acc = 0.f;
    #pragma unroll 8
    for (int l = 0; l < LL; ++l) {
        int idx = cp[l];
        acc += emb[idx * ED + e];
    }
    float* xp = X + (size_t)p * 32;
    xp[e] = acc;
    #pragma unroll
    for (int c = e; c < NC; c += 8) xp[8 + c] = cont[(size_t)p * NC + c];
    if (e == 0) { xp[30] = 0.f; xp[31] = 0.f; }
}

__device__ __forceinline__ float fast_rcp(float x) { return __builtin_amdgcn_rcpf(x); }
__device__ __forceinline__ float fast_sig(float x) { return fast_rcp(1.0f + __expf(-x)); }
__device__ __forceinline__ float fast_tanh(float x) {
    float E = __expf(2.0f * x);
    return 1.0f - 2.0f * fast_rcp(E + 1.0f);
}

// wave64 all-lanes sum: 4 DPP xor-steps (1,2,4,8) + shfl_xor(16,32)
__device__ __forceinline__ float wave_reduce_add(float x) {
    int v;
    v = __builtin_amdgcn_update_dpp(0, __float_as_int(x), 0xB1, 0xF, 0xF, true);  // quad_perm [1,0,3,2]
    x += __int_as_float(v);
    v = __builtin_amdgcn_update_dpp(0, __float_as_int(x), 0x4E, 0xF, 0xF, true);  // quad_perm [2,3,0,1]
    x += __int_as_float(v);
    v = __builtin_amdgcn_update_dpp(0, __float_as_int(x), 0x141, 0xF, 0xF, true); // row_half_mirror
    x += __int_as_float(v);
    v = __builtin_amdgcn_update_dpp(0, __float_as_int(x), 0x140, 0xF, 0xF, true); // row_mirror
    x += __int_as_float(v);
    x += __shfl_xor(x, 16);
    x += __shfl_xor(x, 32);
    return x;
}

__global__ __launch_bounds__(192, 1) void scan_kernel(
    const float* __restrict__ X,
    const int* __restrict__ cat,
    const float* __restrict__ lb, const int* __restrict__ mask,
    const float* __restrict__ dvec, const float* __restrict__ td,
    const float* __restrict__ W_ih, const float* __restrict__ W_hh,
    const float* __restrict__ b_ih, const float* __restrict__ b_hh,
    const float* __restrict__ W_out, const float* __restrict__ b_out,
    float* __restrict__ out)
{
    const int b   = blockIdx.x;
    const int tid = threadIdx.x;

    // ---- LDS: the block's ENTIRE per-step working set (no global ops in loop) ----
    __shared__ __align__(16) float  feat[TT * 32];   // 64 KB; [t][30] = dynamic vfb slot
    __shared__ __align__(16) float4 sc[TT];          // 8 KB: {d, td*24, maskf, lb} per t
    __shared__ float  ccl[TT];                       // 2 KB
    __shared__ float  g1[G3];                        // x-part gates (incl b_ih)
    __shared__ float  g2[G3];                        // h-part gates (incl b_hh)
    __shared__ __align__(16) float h_lds[HH];
    __shared__ __align__(16) float out_lds[TT];      // 2 KB
    __shared__ float kb_lds;

    const size_t bT = (size_t)b * TT;

    // ---- weight rows in registers (pinned; see R2/R3 post-mortems) ----
    float w0[32];
    #pragma unroll
    for (int k = 0; k < 31; ++k) w0[k] = W_ih[tid * 31 + k];
    w0[31] = 0.f;
    float wh[64];
    #pragma unroll
    for (int k = 0; k < 64; ++k) wh[k] = W_hh[tid * 64 + k];
    #pragma unroll
    for (int k = 0; k < 32; ++k) asm volatile("" : "+v"(w0[k]));
    #pragma unroll
    for (int k = 0; k < 64; ++k) asm volatile("" : "+v"(wh[k]));
    const float bi = b_ih[tid];
    const float bh = b_hh[tid];

    float wo0 = 0.f, wo1 = 0.f, wo2 = 0.f, wo3 = 0.f;
    if (tid < HH) {
        wo0 = W_out[0 * HH + tid];
        wo1 = W_out[1 * HH + tid];
        wo2 = W_out[2 * HH + tid];
        wo3 = W_out[3 * HH + tid];
    }
    const float bo0 = b_out[0], bo1 = b_out[1], bo2 = b_out[2], bo3 = b_out[3];

    // ---- prologue: stage feat rows + per-step scalars into LDS ----
    {
        const float4* Xb4 = (const float4*)(X + bT * 32);
        float4* f4 = (float4*)feat;
        #pragma unroll 4
        for (int i = tid; i < TT * 8; i += 192) f4[i] = Xb4[i];
        for (int i = tid; i < TT; i += 192) {
            sc[i] = make_float4(dvec[bT + i], td[bT + i] * 24.0f,
                                (float)mask[bT + i], lb[bT + i]);
        }
        if (tid < HH) h_lds[tid] = 0.f;
    }
    __syncthreads();

    // Kb (replaces kb_kernel): gender ballot over cat[b][0][:], age/weight from feat[0]
    if (tid < HH) {
        int cv = (tid < LL) ? cat[(size_t)b * TT * LL + tid] : 0;
        unsigned long long bal = __ballot(tid < LL && cv == 5);
        float g   = (float)__popcll(bal) * 0.15f + 0.85f;
        float age = feat[10] * 16.936469f + 58.239251f;    // cont c=2
        float wgt = feat[29] * 30.519849f + 87.5752f;      // cont c=21
        if (tid == 0) kb_lds = (140.0f - age) * wgt * g / 72.0f;
    }
    __syncthreads();
    {
        const float Kb = kb_lds;
        for (int i = tid; i < TT; i += 192)
            ccl[i] = Kb * fast_rcp(fmaf(feat[i * 32 + 19], 1.418099f, 1.314668f)); // cont c=11
    }

    float hreg = 0.f;           // wave0 lane j owns h_j
    float Cc = 0.f, Dc = 0.f;   // PK state (uniform across wave 0)

    for (int t = 0; t < TT; ++t) {
        __syncthreads();   // (1) h(t-1), vfb(t), [prologue data] visible

        // gate dots — pure LDS broadcast reads + register FMAs
        const float4* f4 = (const float4*)(feat + t * 32);   // x-part: 32 feats (incl vfb@30, 0@31)
        const float4* h4 = (const float4*)h_lds;             // h-part: 64

        float a1a = 0.f, a1b = 0.f;
        #pragma unroll
        for (int k = 0; k < 8; k += 2) {
            float4 ua = f4[k];
            a1a = fmaf(ua.x, w0[4 * k + 0], a1a);
            a1a = fmaf(ua.y, w0[4 * k + 1], a1a);
            a1a = fmaf(ua.z, w0[4 * k + 2], a1a);
            a1a = fmaf(ua.w, w0[4 * k + 3], a1a);
            float4 ub = f4[k + 1];
            a1b = fmaf(ub.x, w0[4 * k + 4], a1b);
            a1b = fmaf(ub.y, w0[4 * k + 5], a1b);
            a1b = fmaf(ub.z, w0[4 * k + 6], a1b);
            a1b = fmaf(ub.w, w0[4 * k + 7], a1b);
        }
        const float acc1 = bi + a1a + a1b;

        float a2a = 0.f, a2b = 0.f, a2c = 0.f, a2d = 0.f;
        #pragma unroll
        for (int k = 0; k < 16; k += 4) {
            float4 v0 = h4[k], v1 = h4[k + 1], v2 = h4[k + 2], v3 = h4[k + 3];
            a2a = fmaf(v0.x, wh[4 * k + 0],  a2a);
            a2a = fmaf(v0.y, wh[4 * k + 1],  a2a);
            a2a = fmaf(v0.z, wh[4 * k + 2],  a2a);
            a2a = fmaf(v0.w, wh[4 * k + 3],  a2a);
            a2b = fmaf(v1.x, wh[4 * k + 4],  a2b);
            a2b = fmaf(v1.y, wh[4 * k + 5],  a2b);
            a2b = fmaf(v1.z, wh[4 * k + 6],  a2b);
            a2b = fmaf(v1.w, wh[4 * k + 7],  a2b);
            a2c = fmaf(v2.x, wh[4 * k + 8],  a2c);
            a2c = fmaf(v2.y, wh[4 * k + 9],  a2c);
            a2c = fmaf(v2.z, wh[4 * k + 10], a2c);
            a2c = fmaf(v2.w, wh[4 * k + 11], a2c);
            a2d = fmaf(v3.x, wh[4 * k + 12], a2d);
            a2d = fmaf(v3.y, wh[4 * k + 13], a2d);
            a2d = fmaf(v3.z, wh[4 * k + 14], a2d);
            a2d = fmaf(v3.w, wh[4 * k + 15], a2d);
        }
        const float acc2 = bh + ((a2a + a2b) + (a2c + a2d));

        g1[tid] = acc1;
        g2[tid] = acc2;
        __syncthreads();   // (2) gates visible

        if (tid < HH) {
            // GRU update for hidden unit tid (row tid is the r-row: acc1/acc2 local)
            float pre_r = acc1 + acc2;
            float pre_z = g1[tid + HH] + g2[tid + HH];
            float r = fast_sig(pre_r);
            float z = fast_sig(pre_z);
            float n = fast_tanh(fmaf(r, g2[tid + 2 * HH], g1[tid + 2 * HH]));
            hreg = fmaf(z, hreg - n, n);          // (1-z)*n + z*h
            h_lds[tid] = hreg;

            // eta = h . W_out^T : 4 all-lane butterfly sums
            float p0 = wave_reduce_add(hreg * wo0);
            float p1 = wave_reduce_add(hreg * wo1);
            float p2 = wave_reduce_add(hreg * wo2);
            float p3 = wave_reduce_add(hreg * wo3);

            // per-step scalars: uniform LDS broadcast (no global loads)
            const float4 s4 = sc[t];
            const float  cc = ccl[t];
            const float  dd = s4.x, tt = s4.y, mpn = s4.z, lpn = s4.w;

            // PK chain — uniform across wave 0, native exp/rcp/sqrt
            float E1 = __expf(p0 + bo0);
            float E2 = __expf(p1 + bo1);
            float E3 = __expf(p2 + bo2);
            float E4 = __expf(p3 + bo3);
            float v1  = 33.1f * E1;
            float rv1 = fast_rcp(v1);
            float k1  = 3.96f * cc * 0.01f * E2;
            float rrr = 1000.0f * rv1;
            float v2  = 48.3f * E4;
            float R   = (-6.99f / 48.3f) * E3;
            float k2  = R * v2;
            float q   = k1 - k2 - R * v1;
            float disc = fmaf(q, q, 4.0f * k1 * R * v1);
            float delta = __builtin_amdgcn_sqrtf(disc) * rv1;
            float s1  = (k2 - k1 + R * v1) * rv1;
            float lam1 = (s1 - delta) * 0.5f;
            float lam2 = (s1 + delta) * 0.5f;
            float kv  = k2 * rv1;
            float rkv = fast_rcp(kv);
            float C1  = rrr * kv * fast_rcp(lam1 * delta);
            float C2  = -rrr * kv * fast_rcp(lam2 * delta);
            float C3  = -(lam1 - R) * rkv;
            float C4  = -(lam2 - R) * rkv;
            float Cn  = fmaf(Cc + C1, __expf(lam1 * dd), -C1) * __expf(lam1 * (tt - dd));
            float Dn  = fmaf(Dc + C2, __expf(lam2 * dd), -C2) * __expf(lam2 * (tt - dd));
            float An  = fmaf(Cn, C3, Dn * C4);
            Cc = Cn;
            Dc = Dn;
            if (tid == 0) {
                out_lds[t] = An;
                int tn = (t + 1 < TT) ? (t + 1) : t;
                feat[tn * 32 + 30] = An * (1.0f - mpn) + lpn * mpn;   // vfb for t+1
            }
        }
    }

    // ---- epilogue: one coalesced output write ----
    __syncthreads();
    if (tid < TT / 4) {
        ((float4*)(out + bT))[tid] = ((const float4*)out_lds)[tid];
    }
}

extern "C" void kernel_launch(void* const* d_in, const int* in_sizes, int n_in,
                              void* d_out, int out_size, void* d_ws, size_t ws_size,
                              hipStream_t stream) {
    const float* cont  = (const float*)d_in[0];
    const int*   cat   = (const int*)  d_in[1];
    const float* lb    = (const float*)d_in[2];
    const int*   mask  = (const int*)  d_in[3];
    const float* dvec  = (const float*)d_in[4];
    const float* td    = (const float*)d_in[5];
    const float* emb   = (const float*)d_in[6];
    const float* W_ih  = (const float*)d_in[7];
    const float* W_hh  = (const float*)d_in[8];
    const float* b_ih  = (const float*)d_in[9];
    const float* b_hh  = (const float*)d_in[10];
    const float* W_out = (const float*)d_in[11];
    const float* b_out = (const float*)d_in[12];
    float* out = (float*)d_out;

    float* X = (float*)d_ws;

    hipLaunchKernelGGL(xbuild_kernel, dim3((BB * TT) / 32), dim3(256), 0, stream,
                       cont, cat, emb, X);
    hipLaunchKernelGGL(scan_kernel, dim3(BB), dim3(192), 0, stream,
                       X, cat, lb, mask, dvec, td, W_ih, W_hh, b_ih, b_hh, W_out, b_out, out);
}

// Round 5
// 396.976 us; speedup vs baseline: 2.7010x; 1.4856x over previous
//
#include <hip/hip_runtime.h>
#include <math.h>

#define BB 256
#define TT 512
#define LL 40
#define ED 8
#define NC 22
#define HH 64

// ws: X = BB*TT*32 floats (16 MB): [0..7]=emb-sum, [8..29]=cont, [30]=0, [31]=0

__global__ void xbuild_kernel(const float* __restrict__ cont, const int* __restrict__ cat,
                              const float* __restrict__ emb, float* __restrict__ X) {
    int p = blockIdx.x * 32 + (threadIdx.x >> 3);
    int e = threadIdx.x & 7;
    const int* cp = cat + (size_t)p * LL;
    float acc = 0.f;
    #pragma unroll 8
    for (int l = 0; l < LL; ++l) acc += emb[cp[l] * ED + e];
    float* xp = X + (size_t)p * 32;
    xp[e] = acc;
    #pragma unroll
    for (int c = e; c < NC; c += 8) xp[8 + c] = cont[(size_t)p * NC + c];
    if (e == 0) { xp[30] = 0.f; xp[31] = 0.f; }
}

__device__ __forceinline__ float fast_rcp(float x) { return __builtin_amdgcn_rcpf(x); }
__device__ __forceinline__ float fast_sig(float x) { return fast_rcp(1.0f + __expf(-x)); }
__device__ __forceinline__ float fast_tanh(float x) {
    float E = __expf(2.0f * x);
    return 1.0f - 2.0f * fast_rcp(E + 1.0f);
}

__device__ __forceinline__ float dpp_add_xor1(float x) {
    int v = __builtin_amdgcn_update_dpp(0, __float_as_int(x), 0xB1, 0xF, 0xF, true);
    return x + __int_as_float(v);
}
// sum over each 16-lane row (xor1,2,4,8 all row-local DPP)
__device__ __forceinline__ float dpp_reduce16(float x) {
    int v;
    v = __builtin_amdgcn_update_dpp(0, __float_as_int(x), 0xB1, 0xF, 0xF, true);  x += __int_as_float(v);
    v = __builtin_amdgcn_update_dpp(0, __float_as_int(x), 0x4E, 0xF, 0xF, true);  x += __int_as_float(v);
    v = __builtin_amdgcn_update_dpp(0, __float_as_int(x), 0x141, 0xF, 0xF, true); x += __int_as_float(v);
    v = __builtin_amdgcn_update_dpp(0, __float_as_int(x), 0x140, 0xF, 0xF, true); x += __int_as_float(v);
    return x;
}

__global__ __launch_bounds__(192, 1) void scan_kernel(
    const float* __restrict__ X,
    const int* __restrict__ cat,
    const float* __restrict__ lb, const int* __restrict__ mask,
    const float* __restrict__ dvec, const float* __restrict__ td,
    const float* __restrict__ W_ih, const float* __restrict__ W_hh,
    const float* __restrict__ b_ih, const float* __restrict__ b_hh,
    const float* __restrict__ W_out, const float* __restrict__ b_out,
    float* __restrict__ out)
{
    const int b   = blockIdx.x;
    const int tid = threadIdx.x;

    __shared__ __align__(16) float  feat[TT * 32];   // 64 KB, read-only after stage
    __shared__ __align__(16) float4 sc[TT];          // {d, td*24, maskf, lb}
    __shared__ float  ccl[TT];
    __shared__ __align__(16) float  h_lds[HH];
    __shared__ __align__(16) float  out_lds[TT];
    __shared__ float vfb_lds;
    __shared__ float kb_lds;

    const size_t bT = (size_t)b * TT;

    // ---- stage ----
    {
        const float4* Xb4 = (const float4*)(X + bT * 32);
        float4* f4 = (float4*)feat;
        #pragma unroll 4
        for (int i = tid; i < TT * 8; i += 192) f4[i] = Xb4[i];
        for (int i = tid; i < TT; i += 192)
            sc[i] = make_float4(dvec[bT + i], td[bT + i] * 24.0f,
                                (float)mask[bT + i], lb[bT + i]);
        if (tid < HH) h_lds[tid] = 0.f;
        if (tid == 0) vfb_lds = 0.f;
    }
    __syncthreads();
    if (tid < HH) {   // Kb (gender ballot over cat[b][0][:])
        int cv = (tid < LL) ? cat[(size_t)b * TT * LL + tid] : 0;
        unsigned long long bal = __ballot(tid < LL && cv == 5);
        float g   = (float)__popcll(bal) * 0.15f + 0.85f;
        float age = feat[10] * 16.936469f + 58.239251f;   // cont c=2
        float wgt = feat[29] * 30.519849f + 87.5752f;     // cont c=21
        if (tid == 0) kb_lds = (140.0f - age) * wgt * g / 72.0f;
    }
    __syncthreads();
    {
        const float Kb = kb_lds;
        for (int i = tid; i < TT; i += 192)
            ccl[i] = Kb * fast_rcp(fmaf(feat[i * 32 + 19], 1.418099f, 1.314668f)); // cont c=11
    }

    // ---- roles: wave0 (tid<64) = eta+PK; waves1,2 = dots+GRU ----
    const bool isW12 = (tid >= 64);
    const int  L    = tid - 64;      // 0..127 (W12)
    const int  half = L & 1;         // feature half for ALL this lane's rows
    const int  jj   = L >> 1;        // hidden unit owned by this lane pair
    const int  ei   = tid & 15, ej = tid >> 4;   // W0 eta layout

    // W12 weights: 3 rows (jj, jj+64, jj+128), this lane's feature half
    float w0q[3][16], whq[3][32];
    float bsr = 0.f, bsz = 0.f, biN = 0.f, bhN = 0.f;
    float w30r = 0.f, w30z = 0.f, w30n = 0.f;
    float wo0 = 0.f, wo1 = 0.f, wo2 = 0.f, wo3 = 0.f;
    if (isW12) {
        #pragma unroll
        for (int q = 0; q < 3; ++q) {
            const int row = jj + 64 * q;
            #pragma unroll
            for (int k = 0; k < 16; ++k) {
                int f = 16 * half + k;
                w0q[q][k] = (f < 30) ? W_ih[row * 31 + f] : 0.f;  // col30=vfb handled separately
            }
            #pragma unroll
            for (int k = 0; k < 32; ++k)
                whq[q][k] = W_hh[row * 64 + 32 * half + k];
        }
        bsr = b_ih[jj]        + b_hh[jj];
        bsz = b_ih[jj + 64]   + b_hh[jj + 64];
        biN = b_ih[jj + 128];
        bhN = b_hh[jj + 128];
        w30r = W_ih[jj * 31 + 30];
        w30z = W_ih[(jj + 64) * 31 + 30];
        w30n = W_ih[(jj + 128) * 31 + 30];
        #pragma unroll
        for (int q = 0; q < 3; ++q) {
            #pragma unroll
            for (int k = 0; k < 16; ++k) asm volatile("" : "+v"(w0q[q][k]));
            #pragma unroll
            for (int k = 0; k < 32; ++k) asm volatile("" : "+v"(whq[q][k]));
        }
    } else {
        wo0 = W_out[ej * 64 + 4 * ei + 0];
        wo1 = W_out[ej * 64 + 4 * ei + 1];
        wo2 = W_out[ej * 64 + 4 * ei + 2];
        wo3 = W_out[ej * 64 + 4 * ei + 3];
    }
    const float bo0 = b_out[0], bo1 = b_out[1], bo2 = b_out[2], bo3 = b_out[3];

    float hreg = 0.f;                 // W12: h_jj (duplicated in lane pair)
    float Cc = 0.f, Dc = 0.f;         // W0 PK state
    float a10 = 0.f, a11 = 0.f, a12 = 0.f;   // x-part gate sums (rows jj, +64, +128)
    float a20 = 0.f, a21 = 0.f, a22 = 0.f;   // h-part gate sums

    // dots for step t: half-row partials + one DPP-xor1 pair combine
    auto do_dots = [&](int t) {
        const float4* fx = (const float4*)(feat + t * 32) + 4 * half;
        const float4 f0 = fx[0], f1 = fx[1], f2 = fx[2], f3 = fx[3];
        const float4* hx = (const float4*)h_lds + 8 * half;
        const float4 h0 = hx[0], h1 = hx[1], h2 = hx[2], h3 = hx[3];
        const float4 h4 = hx[4], h5 = hx[5], h6 = hx[6], h7 = hx[7];
        float p1[3], p2[3];
        #pragma unroll
        for (int q = 0; q < 3; ++q) {
            float r;
            r = f0.x * w0q[q][0];
            r = fmaf(f0.y, w0q[q][1],  r);
            r = fmaf(f0.z, w0q[q][2],  r);
            r = fmaf(f0.w, w0q[q][3],  r);
            r = fmaf(f1.x, w0q[q][4],  r);
            r = fmaf(f1.y, w0q[q][5],  r);
            r = fmaf(f1.z, w0q[q][6],  r);
            r = fmaf(f1.w, w0q[q][7],  r);
            r = fmaf(f2.x, w0q[q][8],  r);
            r = fmaf(f2.y, w0q[q][9],  r);
            r = fmaf(f2.z, w0q[q][10], r);
            r = fmaf(f2.w, w0q[q][11], r);
            r = fmaf(f3.x, w0q[q][12], r);
            r = fmaf(f3.y, w0q[q][13], r);
            r = fmaf(f3.z, w0q[q][14], r);
            r = fmaf(f3.w, w0q[q][15], r);
            p1[q] = r;
            float s;
            s = h0.x * whq[q][0];
            s = fmaf(h0.y, whq[q][1],  s);
            s = fmaf(h0.z, whq[q][2],  s);
            s = fmaf(h0.w, whq[q][3],  s);
            s = fmaf(h1.x, whq[q][4],  s);
            s = fmaf(h1.y, whq[q][5],  s);
            s = fmaf(h1.z, whq[q][6],  s);
            s = fmaf(h1.w, whq[q][7],  s);
            s = fmaf(h2.x, whq[q][8],  s);
            s = fmaf(h2.y, whq[q][9],  s);
            s = fmaf(h2.z, whq[q][10], s);
            s = fmaf(h2.w, whq[q][11], s);
            s = fmaf(h3.x, whq[q][12], s);
            s = fmaf(h3.y, whq[q][13], s);
            s = fmaf(h3.z, whq[q][14], s);
            s = fmaf(h3.w, whq[q][15], s);
            s = fmaf(h4.x, whq[q][16], s);
            s = fmaf(h4.y, whq[q][17], s);
            s = fmaf(h4.z, whq[q][18], s);
            s = fmaf(h4.w, whq[q][19], s);
            s = fmaf(h5.x, whq[q][20], s);
            s = fmaf(h5.y, whq[q][21], s);
            s = fmaf(h5.z, whq[q][22], s);
            s = fmaf(h5.w, whq[q][23], s);
            s = fmaf(h6.x, whq[q][24], s);
            s = fmaf(h6.y, whq[q][25], s);
            s = fmaf(h6.z, whq[q][26], s);
            s = fmaf(h6.w, whq[q][27], s);
            s = fmaf(h7.x, whq[q][28], s);
            s = fmaf(h7.y, whq[q][29], s);
            s = fmaf(h7.z, whq[q][30], s);
            s = fmaf(h7.w, whq[q][31], s);
            p2[q] = s;
        }
        a10 = dpp_add_xor1(p1[0]);
        a11 = dpp_add_xor1(p1[1]);
        a12 = dpp_add_xor1(p1[2]);
        a20 = dpp_add_xor1(p2[0]);
        a21 = dpp_add_xor1(p2[1]);
        a22 = dpp_add_xor1(p2[2]);
    };

    if (isW12) do_dots(0);   // h=0 staged, vfb=0

    for (int t = 0; t < TT; ++t) {
        // ---- phase alpha: W12 GRU(t) in-register ----
        if (isW12) {
            const float vfb = vfb_lds;
            float tr  = a10 + a20 + bsr;
            float tz  = a11 + a21 + bsz;
            float tnn = a12 + biN;
            float pre_r = fmaf(vfb, w30r, tr);
            float pre_z = fmaf(vfb, w30z, tz);
            float r = fast_sig(pre_r);
            float z = fast_sig(pre_z);
            float inn = fmaf(vfb, w30n, tnn);
            float hn  = a22 + bhN;
            float n = fast_tanh(fmaf(r, hn, inn));
            hreg = fmaf(z, hreg - n, n);
            if (half == 0) h_lds[jj] = hreg;
        }
        __syncthreads();   // B: h(t) visible

        // ---- phase beta: W12 dots(t+1)  ||  W0 eta+PK(t) ----
        if (isW12) {
            if (t + 1 < TT) do_dots(t + 1);
        } else {
            const float4 sv = sc[t];
            const float  cc = ccl[t];
            const float4 hv = ((const float4*)h_lds)[ei];
            float p = hv.x * wo0;
            p = fmaf(hv.y, wo1, p);
            p = fmaf(hv.z, wo2, p);
            p = fmaf(hv.w, wo3, p);
            p = dpp_reduce16(p);   // eta_ej in all lanes of 16-row ej
            const float e0 = __int_as_float(__builtin_amdgcn_readlane(__float_as_int(p), 0));
            const float e1 = __int_as_float(__builtin_amdgcn_readlane(__float_as_int(p), 16));
            const float e2 = __int_as_float(__builtin_amdgcn_readlane(__float_as_int(p), 32));
            const float e3 = __int_as_float(__builtin_amdgcn_readlane(__float_as_int(p), 48));

            float E1 = __expf(e0 + bo0);
            float E2 = __expf(e1 + bo1);
            float E3 = __expf(e2 + bo2);
            float E4 = __expf(e3 + bo3);
            float v1  = 33.1f * E1;
            float rv1 = fast_rcp(v1);
            float k1  = 3.96f * cc * 0.01f * E2;
            float rrr = 1000.0f * rv1;
            float v2  = 48.3f * E4;
            float R   = (-6.99f / 48.3f) * E3;
            float k2  = R * v2;
            float q   = k1 - k2 - R * v1;
            float disc = fmaf(q, q, 4.0f * k1 * R * v1);
            float delta = __builtin_amdgcn_sqrtf(disc) * rv1;
            float sgm  = (k2 - k1 + R * v1) * rv1;
            float lam1 = (sgm - delta) * 0.5f;
            float lam2 = (sgm + delta) * 0.5f;
            float kv  = k2 * rv1;
            float rkv = fast_rcp(kv);
            float C1  = rrr * kv * fast_rcp(lam1 * delta);
            float C2  = -rrr * kv * fast_rcp(lam2 * delta);
            float C3  = -(lam1 - R) * rkv;
            float C4  = -(lam2 - R) * rkv;
            float dd = sv.x, ttv = sv.y;
            float Cn  = fmaf(Cc + C1, __expf(lam1 * dd), -C1) * __expf(lam1 * (ttv - dd));
            float Dn  = fmaf(Dc + C2, __expf(lam2 * dd), -C2) * __expf(lam2 * (ttv - dd));
            float An  = fmaf(Cn, C3, Dn * C4);
            Cc = Cn; Dc = Dn;
            if (tid == 0) {
                out_lds[t] = An;
                vfb_lds = fmaf(An, 1.0f - sv.z, sv.w * sv.z);   // vfb(t+1)
            }
        }
        __syncthreads();   // A: vfb(t+1) visible
    }

    // ---- epilogue: coalesced output write ----
    if (tid < TT / 4) ((float4*)(out + bT))[tid] = ((const float4*)out_lds)[tid];
}

extern "C" void kernel_launch(void* const* d_in, const int* in_sizes, int n_in,
                              void* d_out, int out_size, void* d_ws, size_t ws_size,
                              hipStream_t stream) {
    const float* cont  = (const float*)d_in[0];
    const int*   cat   = (const int*)  d_in[1];
    const float* lb    = (const float*)d_in[2];
    const int*   mask  = (const int*)  d_in[3];
    const float* dvec  = (const float*)d_in[4];
    const float* td    = (const float*)d_in[5];
    const float* emb   = (const float*)d_in[6];
    const float* W_ih  = (const float*)d_in[7];
    const float* W_hh  = (const float*)d_in[8];
    const float* b_ih  = (const float*)d_in[9];
    const float* b_hh  = (const float*)d_in[10];
    const float* W_out = (const float*)d_in[11];
    const float* b_out = (const float*)d_in[12];
    float* out = (float*)d_out;

    float* X = (float*)d_ws;

    hipLaunchKernelGGL(xbuild_kernel, dim3((BB * TT) / 32), dim3(256), 0, stream,
                       cont, cat, emb, X);
    hipLaunchKernelGGL(scan_kernel, dim3(BB), dim3(192), 0, stream,
                       X, cat, lb, mask, dvec, td, W_ih, W_hh, b_ih, b_hh, W_out, b_out, out);
}